// Round 8
// baseline (1115.694 us; speedup 1.0000x reference)
//
#include <hip/hip_runtime.h>
#include <math.h>

// ---------------------------------------------------------------------------
// Temporal GNN. Round 15 = Round 14 with the segment-boundary bug fixed:
//  * tg_agg_sliced: each src-half segment now restarts its cursor at the
//    segment base (r14 advanced p by 4 past a partial tail and skipped up
//    to 3 leading edges of the high bucket -> absmax 2.7e-3).
//  * Design unchanged: column-sliced XCD-phased gather (slice=blockIdx&7 ->
//    one 64-B channel slice per XCD, 6.4 MB working set vs 51 MB plane;
//    CSR bucketed low/high-src to bias instantaneous footprint to 3.2 MB).
//    Falsifiable signature: FETCH_SIZE should drop well below 412 MB.
//  * ft_ln / gemm / CSR build / pool / mlp3 unchanged.
// ---------------------------------------------------------------------------

typedef __attribute__((ext_vector_type(8))) _Float16 half8;  // MFMA A/B frag
typedef __attribute__((ext_vector_type(4))) float floatx4;   // MFMA C/D
typedef __attribute__((ext_vector_type(8))) unsigned short us8; // 16B f16 vec

union HU { _Float16 h; unsigned short u; };

static __device__ __forceinline__ unsigned short f2h(float f) {
    HU x; x.h = (_Float16)f; return x.u;          // v_cvt_f16_f32 (RNE)
}
static __device__ __forceinline__ float h2f(unsigned short s) {
    HU x; x.u = s; return (float)x.h;
}

// async 16B/lane global -> LDS (dest = wave-uniform base + lane*16)
static __device__ __forceinline__ void gl_lds16(const void* g, void* l) {
    __builtin_amdgcn_global_load_lds(
        (const __attribute__((address_space(1))) unsigned int*)(g),
        (__attribute__((address_space(3))) unsigned int*)(l), 16, 0, 0);
}

// sin/cos(ang) for ang up to ~1e5 rad: Cody-Waite 3-term reduction
// + hardware trig on revolutions.
static __device__ __forceinline__ float cw_trig(float ang, bool is_cos) {
    const float i2pi = 0.15915494309189535f;
    const float k = rintf(ang * i2pi);
    float r = fmaf(k, -6.28125f, ang);
    r = fmaf(k, -1.9352436065673828e-3f, r);
    r = fmaf(k, -6.3573019e-8f, r);
    const float rv = r * i2pi;
    return is_cos ? __builtin_amdgcn_cosf(rv) : __builtin_amdgcn_sinf(rv);
}

// Split W[256][256] (k-major) into Bt'[n][512] = [Bh | Bl] f16 (transposed).
__global__ void tg_splitB(const float* __restrict__ W0, const float* __restrict__ W1,
                          const float* __restrict__ W2, const float* __restrict__ W3,
                          unsigned short* __restrict__ B0, unsigned short* __restrict__ B1,
                          unsigned short* __restrict__ B2, unsigned short* __restrict__ B3)
{
    const float* Ws[4] = {W0, W1, W2, W3};
    unsigned short* Bs[4] = {B0, B1, B2, B3};
    const float* W = Ws[blockIdx.z];
    unsigned short* Bt = Bs[blockIdx.z];

    __shared__ float T[64][68];
    const int tk = blockIdx.x * 64, tn = blockIdx.y * 64;
    const int t = threadIdx.x;
#pragma unroll
    for (int j = 0; j < 4; ++j) {
        const int idx = t + 256 * j;
        const int k = idx >> 4, c4 = (idx & 15) * 4;
        const float4 v = *(const float4*)&W[(size_t)(tk + k) * 256 + tn + c4];
        T[k][c4] = v.x; T[k][c4 + 1] = v.y; T[k][c4 + 2] = v.z; T[k][c4 + 3] = v.w;
    }
    __syncthreads();
#pragma unroll
    for (int j = 0; j < 4; ++j) {
        const int idx = t + 256 * j;
        const int n = idx >> 4, q = (idx & 15) * 4;
        unsigned short hh[4], ll[4];
#pragma unroll
        for (int i = 0; i < 4; ++i) {
            const float f = T[q + i][n];
            hh[i] = f2h(f);
            ll[i] = f2h(f - h2f(hh[i]));
        }
        uint2 hp, lp;
        hp.x = (unsigned)hh[0] | ((unsigned)hh[1] << 16);
        hp.y = (unsigned)hh[2] | ((unsigned)hh[3] << 16);
        lp.x = (unsigned)ll[0] | ((unsigned)ll[1] << 16);
        lp.y = (unsigned)ll[2] | ((unsigned)ll[3] << 16);
        unsigned short* row = Bt + (size_t)(tn + n) * 512;
        *(uint2*)&row[tk + q]       = hp;   // Bh
        *(uint2*)&row[256 + tk + q] = lp;   // Bl
    }
}

// ---------------------------------------------------------------------------
// Fused FT GEMM + LayerNorm + PE (round-10 structure, unchanged).
// ---------------------------------------------------------------------------
__global__ __launch_bounds__(256, 2)
void tg_ft_ln(const float* __restrict__ x, const unsigned short* __restrict__ Bt,
              const float* __restrict__ bias, const float* __restrict__ lng,
              const float* __restrict__ lnb, unsigned short* __restrict__ hh, int N)
{
    __shared__ unsigned short sAh[128 * 64];   // 16 KB
    __shared__ unsigned short sAl[128 * 64];   // 16 KB
    __shared__ unsigned short sB[256 * 64];    // 32 KB (Bh then Bl)
    __shared__ float sStats[128][2][2];        // [row][wc][{sum,sumsq}] 2 KB
    __shared__ float sDiv[128];                // PE div table (512 B)

    const int t = threadIdx.x;
    const int w = t >> 6, lane = t & 63;
    const int quad = lane >> 4, l16 = lane & 15;
    const int wr = w >> 1, wc = w & 1;
    const int row0 = blockIdx.x * 128;

    if (t < 128) sDiv[t] = expf((float)(2 * t) * -0.035977892078031970f);

    floatx4 acc[4][8];
#pragma unroll
    for (int i = 0; i < 4; ++i)
#pragma unroll
        for (int j = 0; j < 8; ++j) acc[i][j] = (floatx4){0.f, 0.f, 0.f, 0.f};

    const int arow = t >> 1;
    const int ahalf = t & 1;
    const int srow = lane >> 3;
    const int kgx  = (lane & 7) ^ srow;
    const int rsw  = l16 & 7;

    for (int k4 = 0; k4 < 4; ++k4) {
        const int ka = k4 * 64;
        if (k4) __syncthreads();
        // issue sB = Bh(ka) first (async, overlaps the A chain)
#pragma unroll
        for (int i = 0; i < 8; ++i) {
            const int rr = w * 64 + i * 8;
            gl_lds16(Bt + (size_t)(rr + srow) * 512 + ka + kgx * 8, &sB[rr * 64]);
        }
        // stage A: read f32 x, split to hi/lo f16, swizzled ds_write
        {
            const int grow = row0 + arow;
            const bool ok = grow < N;
            const float* xp = x + (size_t)grow * 256 + ka + ahalf * 32;
#pragma unroll
            for (int j = 0; j < 4; ++j) {
                const int kg = ahalf * 4 + j;
                float4 v0 = {0.f, 0.f, 0.f, 0.f}, v1 = {0.f, 0.f, 0.f, 0.f};
                if (ok) {
                    v0 = *(const float4*)(xp + j * 8);
                    v1 = *(const float4*)(xp + j * 8 + 4);
                }
                const float f[8] = {v0.x, v0.y, v0.z, v0.w, v1.x, v1.y, v1.z, v1.w};
                us8 hi, lo;
#pragma unroll
                for (int i = 0; i < 8; ++i) {
                    hi[i] = f2h(f[i]);
                    lo[i] = f2h(f[i] - h2f(hi[i]));
                }
                const int ad = arow * 64 + ((kg ^ (arow & 7)) << 3);
                *(us8*)&sAh[ad] = hi;
                *(us8*)&sAl[ad] = lo;
            }
        }
        __syncthreads();
        // P0 + P1: Ah.Bh + Al.Bh
#pragma unroll
        for (int ks = 0; ks < 2; ++ks) {
            const int kq = ks * 4 + quad;
            half8 afh[4], afl[4];
#pragma unroll
            for (int rt = 0; rt < 4; ++rt) {
                const int r = wr * 64 + rt * 16 + l16;
                const int off = r * 64 + ((kq ^ rsw) << 3);
                afh[rt] = *(const half8*)&sAh[off];
                afl[rt] = *(const half8*)&sAl[off];
            }
#pragma unroll
            for (int cb = 0; cb < 2; ++cb) {
                half8 bfr[4];
#pragma unroll
                for (int c4 = 0; c4 < 4; ++c4) {
                    const int n = wc * 128 + (cb * 4 + c4) * 16 + l16;
                    bfr[c4] = *(const half8*)&sB[n * 64 + ((kq ^ rsw) << 3)];
                }
#pragma unroll
                for (int c4 = 0; c4 < 4; ++c4)
#pragma unroll
                    for (int rt = 0; rt < 4; ++rt) {
                        acc[rt][cb * 4 + c4] = __builtin_amdgcn_mfma_f32_16x16x32_f16(
                            afh[rt], bfr[c4], acc[rt][cb * 4 + c4], 0, 0, 0);
                        acc[rt][cb * 4 + c4] = __builtin_amdgcn_mfma_f32_16x16x32_f16(
                            afl[rt], bfr[c4], acc[rt][cb * 4 + c4], 0, 0, 0);
                    }
            }
        }
        __syncthreads();
        // stage sB = Bl(ka)
#pragma unroll
        for (int i = 0; i < 8; ++i) {
            const int rr = w * 64 + i * 8;
            gl_lds16(Bt + (size_t)(rr + srow) * 512 + 256 + ka + kgx * 8, &sB[rr * 64]);
        }
        __syncthreads();
        // P2: Ah.Bl
#pragma unroll
        for (int ks = 0; ks < 2; ++ks) {
            const int kq = ks * 4 + quad;
            half8 afh[4];
#pragma unroll
            for (int rt = 0; rt < 4; ++rt) {
                const int r = wr * 64 + rt * 16 + l16;
                afh[rt] = *(const half8*)&sAh[r * 64 + ((kq ^ rsw) << 3)];
            }
#pragma unroll
            for (int cb = 0; cb < 2; ++cb) {
                half8 bfr[4];
#pragma unroll
                for (int c4 = 0; c4 < 4; ++c4) {
                    const int n = wc * 128 + (cb * 4 + c4) * 16 + l16;
                    bfr[c4] = *(const half8*)&sB[n * 64 + ((kq ^ rsw) << 3)];
                }
#pragma unroll
                for (int c4 = 0; c4 < 4; ++c4)
#pragma unroll
                    for (int rt = 0; rt < 4; ++rt)
                        acc[rt][cb * 4 + c4] = __builtin_amdgcn_mfma_f32_16x16x32_f16(
                            afh[rt], bfr[c4], acc[rt][cb * 4 + c4], 0, 0, 0);
            }
        }
    }

    float bs[8], gs[8], bv[8], dv[8];
#pragma unroll
    for (int ct = 0; ct < 8; ++ct) {
        const int gc = wc * 128 + ct * 16 + l16;
        bs[ct] = bias[gc]; gs[ct] = lng[gc]; bv[ct] = lnb[gc];
        dv[ct] = sDiv[gc >> 1];
    }

#pragma unroll
    for (int rt = 0; rt < 4; ++rt) {
#pragma unroll
        for (int i = 0; i < 4; ++i) {
            float s = 0.f, q = 0.f;
#pragma unroll
            for (int ct = 0; ct < 8; ++ct) {
                const float v = fmaxf(acc[rt][ct][i] + bs[ct], 0.f);
                s += v; q += v * v;
            }
#pragma unroll
            for (int m = 1; m < 16; m <<= 1) {
                s += __shfl_xor(s, m, 64);
                q += __shfl_xor(q, m, 64);
            }
            if (l16 == 0) {
                const int rl = wr * 64 + rt * 16 + quad * 4 + i;
                sStats[rl][wc][0] = s;
                sStats[rl][wc][1] = q;
            }
        }
    }
    __syncthreads();

    const bool is_cos = (l16 & 1);
#pragma unroll
    for (int rt = 0; rt < 4; ++rt) {
#pragma unroll
        for (int i = 0; i < 4; ++i) {
            const int rl = wr * 64 + rt * 16 + quad * 4 + i;
            const int gr = row0 + rl;
            if (gr >= N) continue;
            const float sum = sStats[rl][0][0] + sStats[rl][1][0];
            const float sq  = sStats[rl][0][1] + sStats[rl][1][1];
            const float mu  = sum * (1.f / 256.f);
            const float var = sq * (1.f / 256.f) - mu * mu;
            const float rstd = 1.f / sqrtf(var + 1e-5f);
            const float rf = (float)gr;
            unsigned short* orow = hh + (size_t)gr * 256 + wc * 128 + l16;
#pragma unroll
            for (int ct = 0; ct < 8; ++ct) {
                const float v = fmaxf(acc[rt][ct][i] + bs[ct], 0.f);
                const float nrm = (v - mu) * rstd * gs[ct] + bv[ct];
                const float pe = cw_trig(rf * dv[ct], is_cos);
                orow[ct * 16] = f2h(nrm + pe);
            }
        }
    }
}

// GCN GEMM (all 3 layers): A-resident chunk order, XCD-paired col tiles.
__global__ __launch_bounds__(256, 3)
void tg_gemm(const unsigned short* __restrict__ Ph,
             const unsigned short* __restrict__ Bt,
             const float* __restrict__ rowscale,
             unsigned short* __restrict__ out)
{
    __shared__ unsigned short sA[128 * 64], sB[128 * 64];  // 16 KB each

    const int t = threadIdx.x;
    const int w = t >> 6, lane = t & 63;
    const int quad = lane >> 4, l16 = lane & 15;
    const int wr = w >> 1, wc = w & 1;

    const int nwg = gridDim.x;
    const int swq = nwg >> 3, swr = nwg & 7;
    const int xcd = blockIdx.x & 7, oidx = blockIdx.x >> 3;
    const int lg = (xcd < swr ? xcd * (swq + 1)
                              : swr * (swq + 1) + (xcd - swr) * swq) + oidx;
    const int row0 = (lg >> 1) * 128;
    const int col0 = (lg & 1) * 128;

    floatx4 acc[4][4];
#pragma unroll
    for (int i = 0; i < 4; ++i)
#pragma unroll
        for (int j = 0; j < 4; ++j) acc[i][j] = (floatx4){0.f, 0.f, 0.f, 0.f};

    const int srow = lane >> 3;
    const int kgx  = (lane & 7) ^ srow;
    const int rsw  = l16 & 7;

    for (int c = 0; c < 8; ++c) {
        const int ka = (c >> 1) << 6;
        const int kb = ((c & 1) << 8) + ka;
        const bool stA = !(c & 1);
        if (c) __syncthreads();
#pragma unroll
        for (int i = 0; i < 4; ++i) {
            const int rr = w * 32 + i * 8;
            if (stA)
                gl_lds16(Ph + (size_t)(row0 + rr + srow) * 256 + ka + kgx * 8, &sA[rr * 64]);
            gl_lds16(Bt + (size_t)(col0 + rr + srow) * 512 + kb + kgx * 8, &sB[rr * 64]);
        }
        __syncthreads();
#pragma unroll
        for (int ks = 0; ks < 2; ++ks) {
            const int kq = ks * 4 + quad;
            half8 af[4], bfr[4];
#pragma unroll
            for (int rt = 0; rt < 4; ++rt) {
                const int r = wr * 64 + rt * 16 + l16;
                af[rt] = *(const half8*)&sA[r * 64 + ((kq ^ rsw) << 3)];
            }
#pragma unroll
            for (int ct = 0; ct < 4; ++ct) {
                const int n = wc * 64 + ct * 16 + l16;
                bfr[ct] = *(const half8*)&sB[n * 64 + ((kq ^ rsw) << 3)];
            }
#pragma unroll
            for (int ct = 0; ct < 4; ++ct)
#pragma unroll
                for (int rt = 0; rt < 4; ++rt)
                    acc[rt][ct] = __builtin_amdgcn_mfma_f32_16x16x32_f16(
                        af[rt], bfr[ct], acc[rt][ct], 0, 0, 0);
        }
    }

#pragma unroll
    for (int rt = 0; rt < 4; ++rt) {
#pragma unroll
        for (int i = 0; i < 4; ++i) {
            const int gr = row0 + wr * 64 + rt * 16 + quad * 4 + i;
            const float s = rowscale[gr];
#pragma unroll
            for (int ct = 0; ct < 4; ++ct) {
                const int gc = col0 + wc * 64 + ct * 16 + l16;
                out[(size_t)gr * 256 + gc] = f2h(acc[rt][ct][i] * s);
            }
        }
    }
}

// ---------------------------------------------------------------------------
// Column-sliced, XCD-phased aggregate.
// Grid = (Mpad/64) x 8; slice = blockIdx&7 (one 64-B channel slice per XCD
// via round-robin dispatch). 256 threads; 4 lanes per row (16 B each), 16
// rows/wave, 64 rows/block. Edges processed in two src-half segments (CSR
// bucketed); each segment restarts its cursor at the segment base.
// out[row, slice*32 .. +32) = relu(dinv*(self+sum) + bias).
// ---------------------------------------------------------------------------
__global__ __launch_bounds__(256, 4)
void tg_agg_sliced(const unsigned short* __restrict__ hwpIn,
                   const int* __restrict__ rowptr, const int* __restrict__ degLow,
                   const int* __restrict__ col, const float* __restrict__ dinv,
                   const float* __restrict__ bias,
                   unsigned short* __restrict__ out, int N)
{
    const int slice = blockIdx.x & 7;          // -> XCD (round-robin dispatch)
    const int rt    = blockIdx.x >> 3;
    const int t = threadIdx.x;
    const int w = t >> 6, lane = t & 63;
    const int row = rt * 64 + w * 16 + (lane >> 2);
    if (row >= N) return;
    const int q = lane & 3;
    const int cb = slice * 32 + q * 8;         // channel base (8 f16 = 16 B)

    const unsigned short* base = hwpIn + cb;

    // self (accumulate in f32)
    const us8 sv = *(const us8*)(base + (size_t)row * 256);
    float a[8];
#pragma unroll
    for (int j = 0; j < 8; ++j) a[j] = h2f(sv[j]);

    const int beg = rowptr[row];
    const int end = rowptr[row + 1];
    const int mid = beg + degLow[row];

    // process [p0, pe) in 4-wide batches; cursor local to the segment
    auto do_seg = [&](int p0, int pe) {
        for (int p = p0; p < pe; p += 4) {
            const int nn = pe - p;
            int cid[4];
#pragma unroll
            for (int u = 0; u < 4; ++u)
                if (u < nn) cid[u] = col[p + u];
            us8 vv[4];
#pragma unroll
            for (int u = 0; u < 4; ++u)
                if (u < nn) vv[u] = *(const us8*)(base + (size_t)cid[u] * 256);
#pragma unroll
            for (int u = 0; u < 4; ++u) {
                if (u < nn) {
#pragma unroll
                    for (int j = 0; j < 8; ++j) a[j] += h2f(vv[u][j]);
                }
            }
        }
    };
    do_seg(beg, mid);   // low-src edges (bucket 0)
    do_seg(mid, end);   // high-src edges (bucket 1)

    const float di = dinv[row];
    const float4 b0 = *(const float4*)&bias[cb];
    const float4 b1 = *(const float4*)&bias[cb + 4];
    us8 o;
    o[0] = f2h(fmaxf(di * a[0] + b0.x, 0.f));
    o[1] = f2h(fmaxf(di * a[1] + b0.y, 0.f));
    o[2] = f2h(fmaxf(di * a[2] + b0.z, 0.f));
    o[3] = f2h(fmaxf(di * a[3] + b0.w, 0.f));
    o[4] = f2h(fmaxf(di * a[4] + b1.x, 0.f));
    o[5] = f2h(fmaxf(di * a[5] + b1.y, 0.f));
    o[6] = f2h(fmaxf(di * a[6] + b1.z, 0.f));
    o[7] = f2h(fmaxf(di * a[7] + b1.w, 0.f));
    *(us8*)&out[(size_t)row * 256 + cb] = o;
}

// count pass: bucket edges by src-half, record within-bucket slot.
__global__ void tg_count(const int* __restrict__ src, const int* __restrict__ dst,
                         int* __restrict__ degLow, int* __restrict__ degHigh,
                         int* __restrict__ perm, int E, int half)
{
    const int e = blockIdx.x * blockDim.x + threadIdx.x;
    if (e >= E) return;
    const int d = dst[e];
    if (src[e] < half) perm[e] = atomicAdd(&degLow[d], 1);
    else               perm[e] = atomicAdd(&degHigh[d], 1);
}

__global__ void tg_dinv(const int* __restrict__ degLow, const int* __restrict__ degHigh,
                        float* __restrict__ dinv, int N)
{
    const int i = blockIdx.x * blockDim.x + threadIdx.x;
    if (i < N) dinv[i] = 1.f / sqrtf((float)(degLow[i] + degHigh[i] + 1));
}

__global__ void tg_scan1(const int* __restrict__ cntA, const int* __restrict__ cntB,
                         int* __restrict__ out, int* __restrict__ sums, int N)
{
    __shared__ int tmp[1024];
    const int t = threadIdx.x;
    const int gid = blockIdx.x * 1024 + t;
    const int v = (gid < N) ? (cntA[gid] + cntB[gid]) : 0;
    tmp[t] = v;
    __syncthreads();
    for (int o = 1; o < 1024; o <<= 1) {
        const int add = (t >= o) ? tmp[t - o] : 0;
        __syncthreads();
        tmp[t] += add;
        __syncthreads();
    }
    if (gid < N) out[gid] = tmp[t] - v;
    if (t == 1023) sums[blockIdx.x] = tmp[t];
}

__global__ void tg_scan2(int* __restrict__ sums, int nb)
{
    __shared__ int tmp[1024];
    const int t = threadIdx.x;
    const int v = (t < nb) ? sums[t] : 0;
    tmp[t] = v;
    __syncthreads();
    for (int o = 1; o < 1024; o <<= 1) {
        const int add = (t >= o) ? tmp[t - o] : 0;
        __syncthreads();
        tmp[t] += add;
        __syncthreads();
    }
    if (t < nb) sums[t] = tmp[t] - v;
}

__global__ void tg_scan3(int* __restrict__ rowptr, const int* __restrict__ offs,
                         int N, int E)
{
    const int gid = blockIdx.x * 1024 + threadIdx.x;
    if (gid < N) rowptr[gid] += offs[gid >> 10];
    else if (gid == N) rowptr[N] = E;
}

// atomic-free bucketed fill: low-src edges first, then high-src.
__global__ void tg_fill(const int* __restrict__ src, const int* __restrict__ dst,
                        const int* __restrict__ rowptr, const int* __restrict__ degLow,
                        const int* __restrict__ perm, int* __restrict__ col,
                        int E, int half)
{
    const int e = blockIdx.x * blockDim.x + threadIdx.x;
    if (e >= E) return;
    const int s = src[e];
    const int d = dst[e];
    const int pos = (s < half) ? perm[e] : degLow[d] + perm[e];
    col[rowptr[d] + pos] = s;
}

// Mean-pool: block per graph (ranges inlined via binary search on batch).
__global__ void tg_pool(const unsigned short* __restrict__ hh,
                        const int* __restrict__ batch, float* __restrict__ pooled,
                        int N, int G)
{
    __shared__ float sh[4][64][4];
    __shared__ int sBE[2];
    const int g = blockIdx.x;
    const int t = threadIdx.x;
    if (t < 2) {
        const int target = g + t;
        int lo = 0, hi = N;
        while (lo < hi) {
            const int mid = (lo + hi) >> 1;
            if (batch[mid] < target) lo = mid + 1; else hi = mid;
        }
        sBE[t] = lo;
    }
    __syncthreads();
    const int beg = sBE[0], end = sBE[1];
    const int wv = t >> 6, lane = t & 63;
    const int c = lane * 4;
    float s0 = 0.f, s1 = 0.f, s2 = 0.f, s3 = 0.f;
    for (int r = beg + wv; r < end; r += 4) {
        const ushort4 vh = *(const ushort4*)&hh[(size_t)r * 256 + c];
        s0 += h2f(vh.x); s1 += h2f(vh.y); s2 += h2f(vh.z); s3 += h2f(vh.w);
    }
    sh[wv][lane][0] = s0; sh[wv][lane][1] = s1;
    sh[wv][lane][2] = s2; sh[wv][lane][3] = s3;
    __syncthreads();
    if (t < 64) {
        const float inv = 1.f / fmaxf((float)(end - beg), 1.f);
        float4 o;
        o.x = (sh[0][t][0] + sh[1][t][0] + sh[2][t][0] + sh[3][t][0]) * inv;
        o.y = (sh[0][t][1] + sh[1][t][1] + sh[2][t][1] + sh[3][t][1]) * inv;
        o.z = (sh[0][t][2] + sh[1][t][2] + sh[2][t][2] + sh[3][t][2]) * inv;
        o.w = (sh[0][t][3] + sh[1][t][3] + sh[2][t][3] + sh[3][t][3]) * inv;
        *(float4*)&pooled[(size_t)g * 256 + t * 4] = o;
    }
}

// Fused 3-layer classifier MLP: one block per graph.
__global__ __launch_bounds__(256)
void tg_mlp3(const float* __restrict__ pooled,
             const float* __restrict__ W0, const float* __restrict__ b0,
             const float* __restrict__ W1, const float* __restrict__ b1,
             const float* __restrict__ W2, const float* __restrict__ b2,
             float* __restrict__ out, int H2, int Cc)
{
    __shared__ float zin[256];
    __shared__ float z0[256];
    __shared__ float z1[256];
    const int g = blockIdx.x;
    const int t = threadIdx.x;
    zin[t] = pooled[(size_t)g * 256 + t];
    __syncthreads();
    float a = 0.f;
    for (int k = 0; k < 256; ++k) a += zin[k] * W0[(size_t)k * 256 + t];
    z0[t] = fmaxf(a + b0[t], 0.f);
    __syncthreads();
    if (t < H2) {
        float a1 = 0.f;
        for (int k = 0; k < 256; ++k) a1 += z0[k] * W1[(size_t)k * H2 + t];
        z1[t] = fmaxf(a1 + b1[t], 0.f);
    }
    __syncthreads();
    if (t < Cc) {
        float a2 = 0.f;
        for (int k = 0; k < H2; ++k) a2 += z1[k] * W2[(size_t)k * Cc + t];
        out[(size_t)g * Cc + t] = a2 + b2[t];
    }
}

extern "C" void kernel_launch(void* const* d_in, const int* in_sizes, int n_in,
                              void* d_out, int out_size, void* d_ws, size_t ws_size,
                              hipStream_t stream)
{
    const float* x    = (const float*)d_in[0];
    const float* W_ft = (const float*)d_in[1];
    const float* b_ft = (const float*)d_in[2];
    const float* ln_g = (const float*)d_in[3];
    const float* ln_b = (const float*)d_in[4];
    const float* W_g[3] = {(const float*)d_in[5], (const float*)d_in[7], (const float*)d_in[9]};
    const float* b_g[3] = {(const float*)d_in[6], (const float*)d_in[8], (const float*)d_in[10]};
    const float* W_c0 = (const float*)d_in[11];
    const float* b_c0 = (const float*)d_in[12];
    const float* W_c1 = (const float*)d_in[13];
    const float* b_c1 = (const float*)d_in[14];
    const float* W_c2 = (const float*)d_in[15];
    const float* b_c2 = (const float*)d_in[16];
    const int*   edge  = (const int*)d_in[17];
    const int*   batch = (const int*)d_in[18];

    const int N    = in_sizes[18];        // 100000
    const int E    = in_sizes[17] / 2;    // 1600000
    const int Mpad = (N + 127) & ~127;    // 100096
    const int H2   = in_sizes[14];        // 128
    const int Cc   = in_sizes[15] / H2;   // 4
    const int G    = out_size / Cc;       // 512
    const int half = N >> 1;

    const int* srcI = edge;
    const int* dstI = edge + E;

    size_t off = 0;
    auto alloc = [&](size_t bytes) {
        char* p = (char*)d_ws + off;
        off = (off + bytes + 255) & ~(size_t)255;
        return p;
    };
    unsigned short* hh  = (unsigned short*)alloc((size_t)Mpad * 256 * 2);
    unsigned short* P   = (unsigned short*)alloc((size_t)Mpad * 256 * 2);
    unsigned short* Q   = (unsigned short*)alloc((size_t)Mpad * 256 * 2);
    float* dinv    = (float*)alloc((size_t)Mpad * 4);
    int*   degLow  = (int*)alloc((size_t)Mpad * 4);
    int*   degHigh = (int*)alloc((size_t)Mpad * 4);
    int*   rowptr  = (int*)alloc((size_t)(N + 1) * 4);
    int*   perm    = (int*)alloc((size_t)E * 4);
    int*   col     = (int*)alloc((size_t)E * 4);
    int*   bsums   = (int*)alloc(1024 * 4);
    float* pooled  = (float*)alloc((size_t)G * 256 * 4);
    unsigned short* Bt[4];
    for (int i = 0; i < 4; ++i)
        Bt[i] = (unsigned short*)alloc((size_t)256 * 512 * 2);
    (void)ws_size; (void)n_in;

    hipMemsetAsync(degLow, 0, (size_t)Mpad * 4, stream);
    hipMemsetAsync(degHigh, 0, (size_t)Mpad * 4, stream);
    // zero pad rows of planes read by GEMM A-staging
    hipMemsetAsync(hh + (size_t)N * 256, 0, (size_t)(Mpad - N) * 256 * 2, stream);
    hipMemsetAsync(Q + (size_t)N * 256, 0, (size_t)(Mpad - N) * 256 * 2, stream);

    // 0. weight prep
    tg_splitB<<<dim3(4, 4, 4), dim3(256), 0, stream>>>(
        W_ft, W_g[0], W_g[1], W_g[2], Bt[0], Bt[1], Bt[2], Bt[3]);

    // 1. fused feature transform + LayerNorm + PE -> single f16 h plane
    tg_ft_ln<<<dim3(Mpad / 128), dim3(256), 0, stream>>>(
        x, Bt[0], b_ft, ln_g, ln_b, hh, N);

    // 2. degrees + bucketed CSR build (rows = dst, cols = src; low-src first)
    tg_count<<<dim3((E + 255) / 256), dim3(256), 0, stream>>>(
        srcI, dstI, degLow, degHigh, perm, E, half);
    tg_dinv<<<dim3((Mpad + 255) / 256), dim3(256), 0, stream>>>(degLow, degHigh, dinv, Mpad);
    const int NB = (N + 1023) / 1024;
    tg_scan1<<<dim3(NB), dim3(1024), 0, stream>>>(degLow, degHigh, rowptr, bsums, N);
    tg_scan2<<<dim3(1), dim3(1024), 0, stream>>>(bsums, NB);
    tg_scan3<<<dim3((N + 1024) / 1024), dim3(1024), 0, stream>>>(rowptr, bsums, N, E);
    tg_fill<<<dim3((E + 255) / 256), dim3(256), 0, stream>>>(
        srcI, dstI, rowptr, degLow, perm, col, E, half);

    // 3. GCN layers: gemm -> sliced aggregate, x3
    const int nbx = (Mpad / 128) * 2;
    const int nag = (Mpad / 64) * 8;
    tg_gemm<<<dim3(nbx), dim3(256), 0, stream>>>(hh, Bt[1], dinv, P);
    tg_agg_sliced<<<dim3(nag), dim3(256), 0, stream>>>(P, rowptr, degLow, col,
                                                       dinv, b_g[0], Q, N);
    tg_gemm<<<dim3(nbx), dim3(256), 0, stream>>>(Q, Bt[2], dinv, P);
    tg_agg_sliced<<<dim3(nag), dim3(256), 0, stream>>>(P, rowptr, degLow, col,
                                                       dinv, b_g[1], Q, N);
    tg_gemm<<<dim3(nbx), dim3(256), 0, stream>>>(Q, Bt[3], dinv, P);
    tg_agg_sliced<<<dim3(nag), dim3(256), 0, stream>>>(P, rowptr, degLow, col,
                                                       dinv, b_g[2], hh, N);

    // 4. per-graph mean pool (ranges inlined)
    tg_pool<<<dim3(G), dim3(256), 0, stream>>>(hh, batch, pooled, N, G);

    // 5. fused classifier MLP
    tg_mlp3<<<dim3(G), dim3(256), 0, stream>>>(pooled, W_c0, b_c0, W_c1, b_c1,
                                               W_c2, b_c2, (float*)d_out, H2, Cc);
}

// Round 9
// 873.892 us; speedup vs baseline: 1.2767x; 1.2767x over previous
//
#include <hip/hip_runtime.h>
#include <math.h>

// ---------------------------------------------------------------------------
// Temporal GNN. Round 16: best-of-all restore + heterogeneous overlap.
//  * Aggregate: UNSLICED r8/r11 kernel (123us, 3.85 TB/s, FETCH 412MB =
//    measured fabric floor; r15's XCD-slicing raised FETCH to 658MB ->
//    premise falsified, reverted).
//  * NEW tg_ftln_count: ft_ln blocks (compute-bound) + edge-count blocks
//    (atomic-bound) in one grid -> count hides under ft_ln.
//  * NEW tg_gemm_fill: layer-1 GEMM blocks + CSR fill blocks (scatter)
//    in one grid -> fill hides under GEMM. Swizzle bijects over nbx param.
//  * Layers 2,3: plain tg_gemm + tg_aggregate_h (fusion measured neutral).
//  * CSR: single deg array, perm-based atomic-free fill (r11 scheme).
// ---------------------------------------------------------------------------

typedef __attribute__((ext_vector_type(8))) _Float16 half8;  // MFMA A/B frag
typedef __attribute__((ext_vector_type(4))) float floatx4;   // MFMA C/D
typedef __attribute__((ext_vector_type(8))) unsigned short us8; // 16B f16 vec

union HU { _Float16 h; unsigned short u; };

static __device__ __forceinline__ unsigned short f2h(float f) {
    HU x; x.h = (_Float16)f; return x.u;          // v_cvt_f16_f32 (RNE)
}
static __device__ __forceinline__ float h2f(unsigned short s) {
    HU x; x.u = s; return (float)x.h;
}

// async 16B/lane global -> LDS (dest = wave-uniform base + lane*16)
static __device__ __forceinline__ void gl_lds16(const void* g, void* l) {
    __builtin_amdgcn_global_load_lds(
        (const __attribute__((address_space(1))) unsigned int*)(g),
        (__attribute__((address_space(3))) unsigned int*)(l), 16, 0, 0);
}

// sin/cos(ang) for ang up to ~1e5 rad: Cody-Waite 3-term reduction
// + hardware trig on revolutions.
static __device__ __forceinline__ float cw_trig(float ang, bool is_cos) {
    const float i2pi = 0.15915494309189535f;
    const float k = rintf(ang * i2pi);
    float r = fmaf(k, -6.28125f, ang);
    r = fmaf(k, -1.9352436065673828e-3f, r);
    r = fmaf(k, -6.3573019e-8f, r);
    const float rv = r * i2pi;
    return is_cos ? __builtin_amdgcn_cosf(rv) : __builtin_amdgcn_sinf(rv);
}

// Split W[256][256] (k-major) into Bt'[n][512] = [Bh | Bl] f16 (transposed).
__global__ void tg_splitB(const float* __restrict__ W0, const float* __restrict__ W1,
                          const float* __restrict__ W2, const float* __restrict__ W3,
                          unsigned short* __restrict__ B0, unsigned short* __restrict__ B1,
                          unsigned short* __restrict__ B2, unsigned short* __restrict__ B3)
{
    const float* Ws[4] = {W0, W1, W2, W3};
    unsigned short* Bs[4] = {B0, B1, B2, B3};
    const float* W = Ws[blockIdx.z];
    unsigned short* Bt = Bs[blockIdx.z];

    __shared__ float T[64][68];
    const int tk = blockIdx.x * 64, tn = blockIdx.y * 64;
    const int t = threadIdx.x;
#pragma unroll
    for (int j = 0; j < 4; ++j) {
        const int idx = t + 256 * j;
        const int k = idx >> 4, c4 = (idx & 15) * 4;
        const float4 v = *(const float4*)&W[(size_t)(tk + k) * 256 + tn + c4];
        T[k][c4] = v.x; T[k][c4 + 1] = v.y; T[k][c4 + 2] = v.z; T[k][c4 + 3] = v.w;
    }
    __syncthreads();
#pragma unroll
    for (int j = 0; j < 4; ++j) {
        const int idx = t + 256 * j;
        const int n = idx >> 4, q = (idx & 15) * 4;
        unsigned short hh[4], ll[4];
#pragma unroll
        for (int i = 0; i < 4; ++i) {
            const float f = T[q + i][n];
            hh[i] = f2h(f);
            ll[i] = f2h(f - h2f(hh[i]));
        }
        uint2 hp, lp;
        hp.x = (unsigned)hh[0] | ((unsigned)hh[1] << 16);
        hp.y = (unsigned)hh[2] | ((unsigned)hh[3] << 16);
        lp.x = (unsigned)ll[0] | ((unsigned)ll[1] << 16);
        lp.y = (unsigned)ll[2] | ((unsigned)ll[3] << 16);
        unsigned short* row = Bt + (size_t)(tn + n) * 512;
        *(uint2*)&row[tk + q]       = hp;   // Bh
        *(uint2*)&row[256 + tk + q] = lp;   // Bl
    }
}

// ---------------------------------------------------------------------------
// Fused FT GEMM + LayerNorm + PE, with edge-count blocks appended:
// blockIdx < nft -> ft_ln tile; else -> count 2048 edges (8/thread).
// ---------------------------------------------------------------------------
__global__ __launch_bounds__(256, 2)
void tg_ftln_count(const float* __restrict__ x, const unsigned short* __restrict__ Bt,
                   const float* __restrict__ bias, const float* __restrict__ lng,
                   const float* __restrict__ lnb, unsigned short* __restrict__ hh,
                   int N, const int* __restrict__ dst, int* __restrict__ deg,
                   int* __restrict__ perm, int E, int nft)
{
    const int t = threadIdx.x;
    if ((int)blockIdx.x >= nft) {
        // -------- count blocks: perm[e] = slot of edge e within dst row ----
        const int base = ((int)blockIdx.x - nft) * 2048;
#pragma unroll
        for (int j = 0; j < 8; ++j) {
            const int e = base + j * 256 + t;
            if (e < E) perm[e] = atomicAdd(&deg[dst[e]], 1);
        }
        return;
    }

    // -------- ft_ln tile (round-10 structure) --------
    __shared__ unsigned short sAh[128 * 64];   // 16 KB
    __shared__ unsigned short sAl[128 * 64];   // 16 KB
    __shared__ unsigned short sB[256 * 64];    // 32 KB (Bh then Bl)
    __shared__ float sStats[128][2][2];        // [row][wc][{sum,sumsq}] 2 KB
    __shared__ float sDiv[128];                // PE div table (512 B)

    const int w = t >> 6, lane = t & 63;
    const int quad = lane >> 4, l16 = lane & 15;
    const int wr = w >> 1, wc = w & 1;
    const int row0 = blockIdx.x * 128;

    if (t < 128) sDiv[t] = expf((float)(2 * t) * -0.035977892078031970f);

    floatx4 acc[4][8];
#pragma unroll
    for (int i = 0; i < 4; ++i)
#pragma unroll
        for (int j = 0; j < 8; ++j) acc[i][j] = (floatx4){0.f, 0.f, 0.f, 0.f};

    const int arow = t >> 1;
    const int ahalf = t & 1;
    const int srow = lane >> 3;
    const int kgx  = (lane & 7) ^ srow;
    const int rsw  = l16 & 7;

    for (int k4 = 0; k4 < 4; ++k4) {
        const int ka = k4 * 64;
        if (k4) __syncthreads();
        // issue sB = Bh(ka) first (async, overlaps the A chain)
#pragma unroll
        for (int i = 0; i < 8; ++i) {
            const int rr = w * 64 + i * 8;
            gl_lds16(Bt + (size_t)(rr + srow) * 512 + ka + kgx * 8, &sB[rr * 64]);
        }
        // stage A: read f32 x, split to hi/lo f16, swizzled ds_write
        {
            const int grow = row0 + arow;
            const bool ok = grow < N;
            const float* xp = x + (size_t)grow * 256 + ka + ahalf * 32;
#pragma unroll
            for (int j = 0; j < 4; ++j) {
                const int kg = ahalf * 4 + j;
                float4 v0 = {0.f, 0.f, 0.f, 0.f}, v1 = {0.f, 0.f, 0.f, 0.f};
                if (ok) {
                    v0 = *(const float4*)(xp + j * 8);
                    v1 = *(const float4*)(xp + j * 8 + 4);
                }
                const float f[8] = {v0.x, v0.y, v0.z, v0.w, v1.x, v1.y, v1.z, v1.w};
                us8 hi, lo;
#pragma unroll
                for (int i = 0; i < 8; ++i) {
                    hi[i] = f2h(f[i]);
                    lo[i] = f2h(f[i] - h2f(hi[i]));
                }
                const int ad = arow * 64 + ((kg ^ (arow & 7)) << 3);
                *(us8*)&sAh[ad] = hi;
                *(us8*)&sAl[ad] = lo;
            }
        }
        __syncthreads();
        // P0 + P1: Ah.Bh + Al.Bh
#pragma unroll
        for (int ks = 0; ks < 2; ++ks) {
            const int kq = ks * 4 + quad;
            half8 afh[4], afl[4];
#pragma unroll
            for (int rt = 0; rt < 4; ++rt) {
                const int r = wr * 64 + rt * 16 + l16;
                const int off = r * 64 + ((kq ^ rsw) << 3);
                afh[rt] = *(const half8*)&sAh[off];
                afl[rt] = *(const half8*)&sAl[off];
            }
#pragma unroll
            for (int cb = 0; cb < 2; ++cb) {
                half8 bfr[4];
#pragma unroll
                for (int c4 = 0; c4 < 4; ++c4) {
                    const int n = wc * 128 + (cb * 4 + c4) * 16 + l16;
                    bfr[c4] = *(const half8*)&sB[n * 64 + ((kq ^ rsw) << 3)];
                }
#pragma unroll
                for (int c4 = 0; c4 < 4; ++c4)
#pragma unroll
                    for (int rt = 0; rt < 4; ++rt) {
                        acc[rt][cb * 4 + c4] = __builtin_amdgcn_mfma_f32_16x16x32_f16(
                            afh[rt], bfr[c4], acc[rt][cb * 4 + c4], 0, 0, 0);
                        acc[rt][cb * 4 + c4] = __builtin_amdgcn_mfma_f32_16x16x32_f16(
                            afl[rt], bfr[c4], acc[rt][cb * 4 + c4], 0, 0, 0);
                    }
            }
        }
        __syncthreads();
        // stage sB = Bl(ka)
#pragma unroll
        for (int i = 0; i < 8; ++i) {
            const int rr = w * 64 + i * 8;
            gl_lds16(Bt + (size_t)(rr + srow) * 512 + 256 + ka + kgx * 8, &sB[rr * 64]);
        }
        __syncthreads();
        // P2: Ah.Bl
#pragma unroll
        for (int ks = 0; ks < 2; ++ks) {
            const int kq = ks * 4 + quad;
            half8 afh[4];
#pragma unroll
            for (int rt = 0; rt < 4; ++rt) {
                const int r = wr * 64 + rt * 16 + l16;
                afh[rt] = *(const half8*)&sAh[r * 64 + ((kq ^ rsw) << 3)];
            }
#pragma unroll
            for (int cb = 0; cb < 2; ++cb) {
                half8 bfr[4];
#pragma unroll
                for (int c4 = 0; c4 < 4; ++c4) {
                    const int n = wc * 128 + (cb * 4 + c4) * 16 + l16;
                    bfr[c4] = *(const half8*)&sB[n * 64 + ((kq ^ rsw) << 3)];
                }
#pragma unroll
                for (int c4 = 0; c4 < 4; ++c4)
#pragma unroll
                    for (int rt = 0; rt < 4; ++rt)
                        acc[rt][cb * 4 + c4] = __builtin_amdgcn_mfma_f32_16x16x32_f16(
                            afh[rt], bfr[c4], acc[rt][cb * 4 + c4], 0, 0, 0);
            }
        }
    }

    float bs[8], gs[8], bv[8], dv[8];
#pragma unroll
    for (int ct = 0; ct < 8; ++ct) {
        const int gc = wc * 128 + ct * 16 + l16;
        bs[ct] = bias[gc]; gs[ct] = lng[gc]; bv[ct] = lnb[gc];
        dv[ct] = sDiv[gc >> 1];
    }

#pragma unroll
    for (int rt = 0; rt < 4; ++rt) {
#pragma unroll
        for (int i = 0; i < 4; ++i) {
            float s = 0.f, q = 0.f;
#pragma unroll
            for (int ct = 0; ct < 8; ++ct) {
                const float v = fmaxf(acc[rt][ct][i] + bs[ct], 0.f);
                s += v; q += v * v;
            }
#pragma unroll
            for (int m = 1; m < 16; m <<= 1) {
                s += __shfl_xor(s, m, 64);
                q += __shfl_xor(q, m, 64);
            }
            if (l16 == 0) {
                const int rl = wr * 64 + rt * 16 + quad * 4 + i;
                sStats[rl][wc][0] = s;
                sStats[rl][wc][1] = q;
            }
        }
    }
    __syncthreads();

    const bool is_cos = (l16 & 1);
#pragma unroll
    for (int rt = 0; rt < 4; ++rt) {
#pragma unroll
        for (int i = 0; i < 4; ++i) {
            const int rl = wr * 64 + rt * 16 + quad * 4 + i;
            const int gr = row0 + rl;
            if (gr >= N) continue;
            const float sum = sStats[rl][0][0] + sStats[rl][1][0];
            const float sq  = sStats[rl][0][1] + sStats[rl][1][1];
            const float mu  = sum * (1.f / 256.f);
            const float var = sq * (1.f / 256.f) - mu * mu;
            const float rstd = 1.f / sqrtf(var + 1e-5f);
            const float rf = (float)gr;
            unsigned short* orow = hh + (size_t)gr * 256 + wc * 128 + l16;
#pragma unroll
            for (int ct = 0; ct < 8; ++ct) {
                const float v = fmaxf(acc[rt][ct][i] + bs[ct], 0.f);
                const float nrm = (v - mu) * rstd * gs[ct] + bv[ct];
                const float pe = cw_trig(rf * dv[ct], is_cos);
                orow[ct * 16] = f2h(nrm + pe);
            }
        }
    }
}

// GEMM body shared by tg_gemm and tg_gemm_fill (nwg passed explicitly).
static __device__ __forceinline__
void gemm_body(const unsigned short* __restrict__ Ph,
               const unsigned short* __restrict__ Bt,
               const float* __restrict__ rowscale,
               unsigned short* __restrict__ out, int bid, int nwg)
{
    __shared__ unsigned short sA[128 * 64], sB[128 * 64];  // 16 KB each

    const int t = threadIdx.x;
    const int w = t >> 6, lane = t & 63;
    const int quad = lane >> 4, l16 = lane & 15;
    const int wr = w >> 1, wc = w & 1;

    // bijective chunked XCD swizzle over nwg
    const int swq = nwg >> 3, swr = nwg & 7;
    const int xcd = bid & 7, oidx = bid >> 3;
    const int lg = (xcd < swr ? xcd * (swq + 1)
                              : swr * (swq + 1) + (xcd - swr) * swq) + oidx;
    const int row0 = (lg >> 1) * 128;
    const int col0 = (lg & 1) * 128;

    floatx4 acc[4][4];
#pragma unroll
    for (int i = 0; i < 4; ++i)
#pragma unroll
        for (int j = 0; j < 4; ++j) acc[i][j] = (floatx4){0.f, 0.f, 0.f, 0.f};

    const int srow = lane >> 3;
    const int kgx  = (lane & 7) ^ srow;
    const int rsw  = l16 & 7;

    for (int c = 0; c < 8; ++c) {
        const int ka = (c >> 1) << 6;
        const int kb = ((c & 1) << 8) + ka;
        const bool stA = !(c & 1);
        if (c) __syncthreads();
#pragma unroll
        for (int i = 0; i < 4; ++i) {
            const int rr = w * 32 + i * 8;
            if (stA)
                gl_lds16(Ph + (size_t)(row0 + rr + srow) * 256 + ka + kgx * 8, &sA[rr * 64]);
            gl_lds16(Bt + (size_t)(col0 + rr + srow) * 512 + kb + kgx * 8, &sB[rr * 64]);
        }
        __syncthreads();
#pragma unroll
        for (int ks = 0; ks < 2; ++ks) {
            const int kq = ks * 4 + quad;
            half8 af[4], bfr[4];
#pragma unroll
            for (int rt = 0; rt < 4; ++rt) {
                const int r = wr * 64 + rt * 16 + l16;
                af[rt] = *(const half8*)&sA[r * 64 + ((kq ^ rsw) << 3)];
            }
#pragma unroll
            for (int ct = 0; ct < 4; ++ct) {
                const int n = wc * 64 + ct * 16 + l16;
                bfr[ct] = *(const half8*)&sB[n * 64 + ((kq ^ rsw) << 3)];
            }
#pragma unroll
            for (int ct = 0; ct < 4; ++ct)
#pragma unroll
                for (int rt = 0; rt < 4; ++rt)
                    acc[rt][ct] = __builtin_amdgcn_mfma_f32_16x16x32_f16(
                        af[rt], bfr[ct], acc[rt][ct], 0, 0, 0);
        }
    }

#pragma unroll
    for (int rt = 0; rt < 4; ++rt) {
#pragma unroll
        for (int i = 0; i < 4; ++i) {
            const int gr = row0 + wr * 64 + rt * 16 + quad * 4 + i;
            const float s = rowscale[gr];
#pragma unroll
            for (int ct = 0; ct < 4; ++ct) {
                const int gc = col0 + wc * 64 + ct * 16 + l16;
                out[(size_t)gr * 256 + gc] = f2h(acc[rt][ct][i] * s);
            }
        }
    }
}

// GCN GEMM (layers 2,3): hwp = f16((h@W) * dinv_row)
__global__ __launch_bounds__(256, 3)
void tg_gemm(const unsigned short* __restrict__ Ph,
             const unsigned short* __restrict__ Bt,
             const float* __restrict__ rowscale,
             unsigned short* __restrict__ out)
{
    gemm_body(Ph, Bt, rowscale, out, (int)blockIdx.x, (int)gridDim.x);
}

// Layer-1 GEMM + CSR fill: blockIdx < nbx -> GEMM tile; else -> fill 2048 edges.
__global__ __launch_bounds__(256, 3)
void tg_gemm_fill(const unsigned short* __restrict__ Ph,
                  const unsigned short* __restrict__ Bt,
                  const float* __restrict__ rowscale,
                  unsigned short* __restrict__ out,
                  const int* __restrict__ src, const int* __restrict__ dst,
                  const int* __restrict__ rowptr, const int* __restrict__ perm,
                  int* __restrict__ col, int E, int nbx)
{
    const int t = threadIdx.x;
    if ((int)blockIdx.x >= nbx) {
        const int base = ((int)blockIdx.x - nbx) * 2048;
#pragma unroll
        for (int j = 0; j < 8; ++j) {
            const int e = base + j * 256 + t;
            if (e < E) col[rowptr[dst[e]] + perm[e]] = src[e];
        }
        return;
    }
    gemm_body(Ph, Bt, rowscale, out, (int)blockIdx.x, nbx);
}

__global__ void tg_dinv(const int* __restrict__ deg, float* __restrict__ dinv, int N)
{
    const int i = blockIdx.x * blockDim.x + threadIdx.x;
    if (i < N) dinv[i] = 1.f / sqrtf((float)(deg[i] + 1));  // +1 self-loop
}

__global__ void tg_scan1(const int* __restrict__ cnt, int* __restrict__ out,
                         int* __restrict__ sums, int N)
{
    __shared__ int tmp[1024];
    const int t = threadIdx.x;
    const int gid = blockIdx.x * 1024 + t;
    const int v = (gid < N) ? cnt[gid] : 0;
    tmp[t] = v;
    __syncthreads();
    for (int o = 1; o < 1024; o <<= 1) {
        const int add = (t >= o) ? tmp[t - o] : 0;
        __syncthreads();
        tmp[t] += add;
        __syncthreads();
    }
    if (gid < N) out[gid] = tmp[t] - v;
    if (t == 1023) sums[blockIdx.x] = tmp[t];
}

__global__ void tg_scan2(int* __restrict__ sums, int nb)
{
    __shared__ int tmp[1024];
    const int t = threadIdx.x;
    const int v = (t < nb) ? sums[t] : 0;
    tmp[t] = v;
    __syncthreads();
    for (int o = 1; o < 1024; o <<= 1) {
        const int add = (t >= o) ? tmp[t - o] : 0;
        __syncthreads();
        tmp[t] += add;
        __syncthreads();
    }
    if (t < nb) sums[t] = tmp[t] - v;
}

__global__ void tg_scan3(int* __restrict__ rowptr, const int* __restrict__ offs,
                         int N, int E)
{
    const int gid = blockIdx.x * 1024 + threadIdx.x;
    if (gid < N) rowptr[gid] += offs[gid >> 10];
    else if (gid == N) rowptr[N] = E;
}

// Aggregate (unsliced, measured fabric floor: 123us, 3.85 TB/s, FETCH 412MB).
// 2 rows/wave, 32 lanes/row, 16B dwordx4 gathers, index double-buffer.
__global__ void tg_aggregate_h(const unsigned short* __restrict__ hwpb,
                               const int* __restrict__ rowptr, const int* __restrict__ col,
                               const float* __restrict__ dinv, const float* __restrict__ bias,
                               unsigned short* __restrict__ hh, int N)
{
    const int gt = blockIdx.x * blockDim.x + threadIdx.x;
    const int row = gt >> 5;               // 32-thread group per row
    if (row >= N) return;
    const int hl = gt & 31;
    const int c = hl * 8;                  // 8 halves = 16 B per lane

    const unsigned short* base = hwpb + c;
    const int beg = rowptr[row], end = rowptr[row + 1];

    const us8 sv = *(const us8*)(base + (size_t)row * 256);
    float a[8];
#pragma unroll
    for (int j = 0; j < 8; ++j) a[j] = h2f(sv[j]);

    int p = beg;
    int rem = end - beg;
    int c0[8];
    if (rem >= 8) {
#pragma unroll
        for (int u = 0; u < 8; ++u) c0[u] = col[p + u];
    }
    while (rem >= 8) {
        int c1[8];
        const bool more = rem >= 16;
        if (more) {
#pragma unroll
            for (int u = 0; u < 8; ++u) c1[u] = col[p + 8 + u];
        }
        us8 v[8];
#pragma unroll
        for (int u = 0; u < 8; ++u)
            v[u] = *(const us8*)(base + (size_t)c0[u] * 256);
#pragma unroll
        for (int u = 0; u < 8; ++u)
#pragma unroll
            for (int j = 0; j < 8; ++j) a[j] += h2f(v[u][j]);
        if (more) {
#pragma unroll
            for (int u = 0; u < 8; ++u) c0[u] = c1[u];
        }
        p += 8; rem -= 8;
    }
    if (rem > 0) {
        const int last = end - 1;
        int ci[8];
#pragma unroll
        for (int u = 0; u < 8; ++u) {
            const int pp = (p + u < last) ? p + u : last;   // clamp: no OOB
            ci[u] = col[pp];
        }
        us8 v[8];
#pragma unroll
        for (int u = 0; u < 8; ++u)
            v[u] = *(const us8*)(base + (size_t)(u < rem ? ci[u] : row) * 256);
#pragma unroll
        for (int u = 0; u < 8; ++u) {
            if (u < rem) {
#pragma unroll
                for (int j = 0; j < 8; ++j) a[j] += h2f(v[u][j]);
            }
        }
    }

    const float di = dinv[row];
    const float4 b0 = *(const float4*)&bias[c];
    const float4 b1 = *(const float4*)&bias[c + 4];
    us8 o;
    o[0] = f2h(fmaxf(di * a[0] + b0.x, 0.f));
    o[1] = f2h(fmaxf(di * a[1] + b0.y, 0.f));
    o[2] = f2h(fmaxf(di * a[2] + b0.z, 0.f));
    o[3] = f2h(fmaxf(di * a[3] + b0.w, 0.f));
    o[4] = f2h(fmaxf(di * a[4] + b1.x, 0.f));
    o[5] = f2h(fmaxf(di * a[5] + b1.y, 0.f));
    o[6] = f2h(fmaxf(di * a[6] + b1.z, 0.f));
    o[7] = f2h(fmaxf(di * a[7] + b1.w, 0.f));
    *(us8*)&hh[(size_t)row * 256 + c] = o;
}

// Mean-pool: block per graph (ranges inlined via binary search on batch).
__global__ void tg_pool(const unsigned short* __restrict__ hh,
                        const int* __restrict__ batch, float* __restrict__ pooled,
                        int N, int G)
{
    __shared__ float sh[4][64][4];
    __shared__ int sBE[2];
    const int g = blockIdx.x;
    const int t = threadIdx.x;
    if (t < 2) {
        const int target = g + t;
        int lo = 0, hi = N;
        while (lo < hi) {
            const int mid = (lo + hi) >> 1;
            if (batch[mid] < target) lo = mid + 1; else hi = mid;
        }
        sBE[t] = lo;
    }
    __syncthreads();
    const int beg = sBE[0], end = sBE[1];
    const int wv = t >> 6, lane = t & 63;
    const int c = lane * 4;
    float s0 = 0.f, s1 = 0.f, s2 = 0.f, s3 = 0.f;
    for (int r = beg + wv; r < end; r += 4) {
        const ushort4 vh = *(const ushort4*)&hh[(size_t)r * 256 + c];
        s0 += h2f(vh.x); s1 += h2f(vh.y); s2 += h2f(vh.z); s3 += h2f(vh.w);
    }
    sh[wv][lane][0] = s0; sh[wv][lane][1] = s1;
    sh[wv][lane][2] = s2; sh[wv][lane][3] = s3;
    __syncthreads();
    if (t < 64) {
        const float inv = 1.f / fmaxf((float)(end - beg), 1.f);
        float4 o;
        o.x = (sh[0][t][0] + sh[1][t][0] + sh[2][t][0] + sh[3][t][0]) * inv;
        o.y = (sh[0][t][1] + sh[1][t][1] + sh[2][t][1] + sh[3][t][1]) * inv;
        o.z = (sh[0][t][2] + sh[1][t][2] + sh[2][t][2] + sh[3][t][2]) * inv;
        o.w = (sh[0][t][3] + sh[1][t][3] + sh[2][t][3] + sh[3][t][3]) * inv;
        *(float4*)&pooled[(size_t)g * 256 + t * 4] = o;
    }
}

// Fused 3-layer classifier MLP: one block per graph.
__global__ __launch_bounds__(256)
void tg_mlp3(const float* __restrict__ pooled,
             const float* __restrict__ W0, const float* __restrict__ b0,
             const float* __restrict__ W1, const float* __restrict__ b1,
             const float* __restrict__ W2, const float* __restrict__ b2,
             float* __restrict__ out, int H2, int Cc)
{
    __shared__ float zin[256];
    __shared__ float z0[256];
    __shared__ float z1[256];
    const int g = blockIdx.x;
    const int t = threadIdx.x;
    zin[t] = pooled[(size_t)g * 256 + t];
    __syncthreads();
    float a = 0.f;
    for (int k = 0; k < 256; ++k) a += zin[k] * W0[(size_t)k * 256 + t];
    z0[t] = fmaxf(a + b0[t], 0.f);
    __syncthreads();
    if (t < H2) {
        float a1 = 0.f;
        for (int k = 0; k < 256; ++k) a1 += z0[k] * W1[(size_t)k * H2 + t];
        z1[t] = fmaxf(a1 + b1[t], 0.f);
    }
    __syncthreads();
    if (t < Cc) {
        float a2 = 0.f;
        for (int k = 0; k < H2; ++k) a2 += z1[k] * W2[(size_t)k * Cc + t];
        out[(size_t)g * Cc + t] = a2 + b2[t];
    }
}

extern "C" void kernel_launch(void* const* d_in, const int* in_sizes, int n_in,
                              void* d_out, int out_size, void* d_ws, size_t ws_size,
                              hipStream_t stream)
{
    const float* x    = (const float*)d_in[0];
    const float* W_ft = (const float*)d_in[1];
    const float* b_ft = (const float*)d_in[2];
    const float* ln_g = (const float*)d_in[3];
    const float* ln_b = (const float*)d_in[4];
    const float* W_g[3] = {(const float*)d_in[5], (const float*)d_in[7], (const float*)d_in[9]};
    const float* b_g[3] = {(const float*)d_in[6], (const float*)d_in[8], (const float*)d_in[10]};
    const float* W_c0 = (const float*)d_in[11];
    const float* b_c0 = (const float*)d_in[12];
    const float* W_c1 = (const float*)d_in[13];
    const float* b_c1 = (const float*)d_in[14];
    const float* W_c2 = (const float*)d_in[15];
    const float* b_c2 = (const float*)d_in[16];
    const int*   edge  = (const int*)d_in[17];
    const int*   batch = (const int*)d_in[18];

    const int N    = in_sizes[18];        // 100000
    const int E    = in_sizes[17] / 2;    // 1600000
    const int Mpad = (N + 127) & ~127;    // 100096
    const int H2   = in_sizes[14];        // 128
    const int Cc   = in_sizes[15] / H2;   // 4
    const int G    = out_size / Cc;       // 512

    const int* srcI = edge;
    const int* dstI = edge + E;

    size_t off = 0;
    auto alloc = [&](size_t bytes) {
        char* p = (char*)d_ws + off;
        off = (off + bytes + 255) & ~(size_t)255;
        return p;
    };
    unsigned short* hh  = (unsigned short*)alloc((size_t)Mpad * 256 * 2);
    unsigned short* P   = (unsigned short*)alloc((size_t)Mpad * 256 * 2);
    unsigned short* Q   = (unsigned short*)alloc((size_t)Mpad * 256 * 2);
    float* dinv   = (float*)alloc((size_t)Mpad * 4);
    int*   deg    = (int*)alloc((size_t)Mpad * 4);
    int*   rowptr = (int*)alloc((size_t)(N + 1) * 4);
    int*   perm   = (int*)alloc((size_t)E * 4);
    int*   col    = (int*)alloc((size_t)E * 4);
    int*   bsums  = (int*)alloc(1024 * 4);
    float* pooled = (float*)alloc((size_t)G * 256 * 4);
    unsigned short* Bt[4];
    for (int i = 0; i < 4; ++i)
        Bt[i] = (unsigned short*)alloc((size_t)256 * 512 * 2);
    (void)ws_size; (void)n_in;

    hipMemsetAsync(deg, 0, (size_t)Mpad * 4, stream);
    // zero pad rows of planes read by GEMM A-staging
    hipMemsetAsync(hh + (size_t)N * 256, 0, (size_t)(Mpad - N) * 256 * 2, stream);
    hipMemsetAsync(Q + (size_t)N * 256, 0, (size_t)(Mpad - N) * 256 * 2, stream);

    // 0. weight prep
    tg_splitB<<<dim3(4, 4, 4), dim3(256), 0, stream>>>(
        W_ft, W_g[0], W_g[1], W_g[2], Bt[0], Bt[1], Bt[2], Bt[3]);

    // 1. ft_ln tiles + edge-count blocks (heterogeneous grid)
    const int nft  = Mpad / 128;               // 782 ft_ln tiles
    const int ncnt = (E + 2047) / 2048;        // 782 count blocks
    tg_ftln_count<<<dim3(nft + ncnt), dim3(256), 0, stream>>>(
        x, Bt[0], b_ft, ln_g, ln_b, hh, N, dstI, deg, perm, E, nft);

    // 2. dinv + rowptr scans
    tg_dinv<<<dim3((Mpad + 255) / 256), dim3(256), 0, stream>>>(deg, dinv, Mpad);
    const int NB = (N + 1023) / 1024;
    tg_scan1<<<dim3(NB), dim3(1024), 0, stream>>>(deg, rowptr, bsums, N);
    tg_scan2<<<dim3(1), dim3(1024), 0, stream>>>(bsums, NB);
    tg_scan3<<<dim3((N + 1024) / 1024), dim3(1024), 0, stream>>>(rowptr, bsums, N, E);

    // 3. layer-1 GEMM + CSR fill (heterogeneous grid), then agg;
    //    layers 2,3 plain gemm + agg
    const int nbx = (Mpad / 128) * 2;
    const int nfl = (E + 2047) / 2048;
    tg_gemm_fill<<<dim3(nbx + nfl), dim3(256), 0, stream>>>(
        hh, Bt[1], dinv, P, srcI, dstI, rowptr, perm, col, E, nbx);
    tg_aggregate_h<<<dim3((N + 7) / 8), dim3(256), 0, stream>>>(P, rowptr, col, dinv,
                                                                b_g[0], Q, N);
    tg_gemm<<<dim3(nbx), dim3(256), 0, stream>>>(Q, Bt[2], dinv, P);
    tg_aggregate_h<<<dim3((N + 7) / 8), dim3(256), 0, stream>>>(P, rowptr, col, dinv,
                                                                b_g[1], Q, N);
    tg_gemm<<<dim3(nbx), dim3(256), 0, stream>>>(Q, Bt[3], dinv, P);
    tg_aggregate_h<<<dim3((N + 7) / 8), dim3(256), 0, stream>>>(P, rowptr, col, dinv,
                                                                b_g[2], hh, N);

    // 4. per-graph mean pool (ranges inlined)
    tg_pool<<<dim3(G), dim3(256), 0, stream>>>(hh, batch, pooled, N, G);

    // 5. fused classifier MLP
    tg_mlp3<<<dim3(G), dim3(256), 0, stream>>>(pooled, W_c0, b_c0, W_c1, b_c1,
                                               W_c2, b_c2, (float*)d_out, H2, Cc);
}